// Round 5
// baseline (1026.774 us; speedup 1.0000x reference)
//
#include <hip/hip_runtime.h>
#include <math.h>

// ---------------------------------------------------------------------------
// TransNeXt aggregated attention. Round 5: round-4 structure with the lts
// staging bug fixed (elements 256..287 were never written -> garbage LDS).
// B=4, H=W=64, C=256, NH=8, hd=32, LOCAL_LEN=9, pool 8x8=64
// ---------------------------------------------------------------------------

typedef unsigned short ushort_t;
typedef __attribute__((ext_vector_type(8))) short short8;
typedef __attribute__((ext_vector_type(4))) float f32x4;

static __device__ __forceinline__ unsigned short f2bf(float f) {
    unsigned int u = __float_as_uint(f);
    unsigned int lsb = (u >> 16) & 1u;
    u += 0x7fffu + lsb;                 // round-to-nearest-even
    return (unsigned short)(u >> 16);
}
static __device__ __forceinline__ float bf2f(unsigned short h) {
    return __uint_as_float(((unsigned int)h) << 16);
}

#define GLOAD16(g, l)                                                        \
    __builtin_amdgcn_global_load_lds(                                        \
        (const __attribute__((address_space(1))) unsigned int*)(g),          \
        (__attribute__((address_space(3))) unsigned int*)(l), 16, 0, 0)

// ---------------------------------------------------------------------------
// MFMA GEMM: C = A @ W^T + bias. 128x128 tile, BK=32.
// ---------------------------------------------------------------------------
template <bool SPLIT>
__global__ __launch_bounds__(256) void mfma_gemm(
    const ushort_t* __restrict__ Ahi_g, const ushort_t* __restrict__ Alo_g,
    const ushort_t* __restrict__ Bhi_g, const ushort_t* __restrict__ Blo_g,
    const float* __restrict__ bias, float* __restrict__ out0,
    float* __restrict__ out1, int mode)
{
    const int K = 256;
    __shared__ ushort_t Ah[128 * 32];
    __shared__ ushort_t Bh[128 * 32];
    __shared__ ushort_t Al[SPLIT ? 128 * 32 : 8];
    __shared__ ushort_t Bl[SPLIT ? 128 * 32 : 8];

    const int t = threadIdx.x;
    const int w = t >> 6;
    const int lane = t & 63;
    const int bm = blockIdx.y * 128;
    const int bn = blockIdx.x * 128;
    const int wm = (w >> 1) * 64;
    const int wn = (w & 1) * 64;

    f32x4 acc[4][4];
#pragma unroll
    for (int i = 0; i < 4; ++i)
#pragma unroll
        for (int j = 0; j < 4; ++j) acc[i][j] = f32x4{0.f, 0.f, 0.f, 0.f};

    const int lrow = lane >> 2;
    const int lk8  = (lane & 3) * 8;

    for (int k0 = 0; k0 < K; k0 += 32) {
#pragma unroll
        for (int r = 0; r < 2; ++r) {
            const int rowoff = r * 64 + w * 16;
            const int arow = bm + rowoff + lrow;
            const int brow = bn + rowoff + lrow;
            const unsigned ldsoff = (unsigned)rowoff * 32;
            GLOAD16(Ahi_g + (size_t)arow * K + k0 + lk8, &Ah[ldsoff]);
            GLOAD16(Bhi_g + (size_t)brow * K + k0 + lk8, &Bh[ldsoff]);
            if (SPLIT) {
                GLOAD16(Alo_g + (size_t)arow * K + k0 + lk8, &Al[ldsoff]);
                GLOAD16(Blo_g + (size_t)brow * K + k0 + lk8, &Bl[ldsoff]);
            }
        }
        __syncthreads();

        const int fr = lane & 15;
        const int fq = (lane >> 4) * 8;
        short8 ah[4], bh[4], al[4], bl[4];
#pragma unroll
        for (int i = 0; i < 4; ++i) {
            ah[i] = *(const short8*)&Ah[(wm + i * 16 + fr) * 32 + fq];
            if (SPLIT) al[i] = *(const short8*)&Al[(wm + i * 16 + fr) * 32 + fq];
        }
#pragma unroll
        for (int j = 0; j < 4; ++j) {
            bh[j] = *(const short8*)&Bh[(wn + j * 16 + fr) * 32 + fq];
            if (SPLIT) bl[j] = *(const short8*)&Bl[(wn + j * 16 + fr) * 32 + fq];
        }
#pragma unroll
        for (int i = 0; i < 4; ++i)
#pragma unroll
            for (int j = 0; j < 4; ++j) {
                acc[i][j] = __builtin_amdgcn_mfma_f32_16x16x32_bf16(ah[i], bh[j], acc[i][j], 0, 0, 0);
                if (SPLIT) {
                    acc[i][j] = __builtin_amdgcn_mfma_f32_16x16x32_bf16(ah[i], bl[j], acc[i][j], 0, 0, 0);
                    acc[i][j] = __builtin_amdgcn_mfma_f32_16x16x32_bf16(al[i], bh[j], acc[i][j], 0, 0, 0);
                }
            }
        __syncthreads();
    }

    const int fr = lane & 15;
    const int q4 = (lane >> 4) * 4;
#pragma unroll
    for (int i = 0; i < 4; ++i) {
#pragma unroll
        for (int j = 0; j < 4; ++j) {
            const int col = bn + wn + j * 16 + fr;
            const float bv = bias[col];
#pragma unroll
            for (int r = 0; r < 4; ++r) {
                const int row = bm + wm + i * 16 + q4 + r;
                float v = acc[i][j][r] + bv;
                if (mode == 0) {
                    if (col < 256) out0[(size_t)row * 256 + col] = v;
                    else           out1[(size_t)row * 512 + (col - 256)] = v;
                } else if (mode == 1) {
                    if (col < 256) out0[(size_t)row * 512 + 256 + col] = v;
                    else {
                        v = 0.5f * v * (1.0f + erff(v * 0.70710678118654752f));
                        out1[(size_t)row * 256 + (col - 256)] = v;
                    }
                } else {
                    out0[(size_t)row * 256 + col] = v;
                }
            }
        }
    }
}

// x (fp32) -> hi/lo bf16 pair
__global__ __launch_bounds__(256) void cast_split(
    const float4* __restrict__ x, ushort4* __restrict__ hi,
    ushort4* __restrict__ lo, int n4)
{
    int i = blockIdx.x * 256 + threadIdx.x;
    if (i >= n4) return;
    float4 v = x[i];
    ushort4 h, l;
    h.x = f2bf(v.x); l.x = f2bf(v.x - bf2f(h.x));
    h.y = f2bf(v.y); l.y = f2bf(v.y - bf2f(h.y));
    h.z = f2bf(v.z); l.z = f2bf(v.z - bf2f(h.z));
    h.w = f2bf(v.w); l.w = f2bf(v.w - bf2f(h.w));
    hi[i] = h; lo[i] = l;
}

// Build packed weight/bias buffers.
__global__ __launch_bounds__(256) void pack_weights(
    const float* __restrict__ qw, const float* __restrict__ kvw,
    const float* __restrict__ srw, const float* __restrict__ pw,
    const float* __restrict__ qb, const float* __restrict__ kvb,
    const float* __restrict__ srb,
    ushort_t* __restrict__ Wqkh, ushort_t* __restrict__ Wqkl,
    ushort_t* __restrict__ Wvs, ushort_t* __restrict__ Pw,
    float* __restrict__ bqk, float* __restrict__ bvs)
{
    int idx = blockIdx.x * 256 + threadIdx.x;
    if (idx < 131072) {
        int nn = idx >> 8, k = idx & 255;
        float a = (nn < 256) ? qw[nn * 256 + k] : kvw[(nn - 256) * 256 + k];
        unsigned short h = f2bf(a);
        Wqkh[idx] = h;
        Wqkl[idx] = f2bf(a - bf2f(h));
        float b = (nn < 256) ? kvw[(nn + 256) * 256 + k] : srw[(nn - 256) * 256 + k];
        Wvs[idx] = f2bf(b);
    }
    if (idx < 65536) Pw[idx] = f2bf(pw[idx]);
    if (idx < 512) bqk[idx] = (idx < 256) ? qb[idx] : kvb[idx - 256];
    else if (idx < 1024) {
        int r = idx - 512;
        bvs[r] = (r < 256) ? kvb[r + 256] : srb[r - 256];
    }
}

// ------------------------- fp32 tile GEMM (kv_p only) -----------------------
#define BM 64
#define BN 64
#define BKK 16
__global__ __launch_bounds__(256) void gemm_bias_act(
    const float* __restrict__ A, const float* __restrict__ Wt,
    const float* __restrict__ bias, float* __restrict__ Cmat,
    int M, int N, int K, int act)
{
    __shared__ float As[BKK][BM + 4];
    __shared__ float Bs[BKK][BN + 4];
    const int tid = threadIdx.x;
    const int bm = blockIdx.y * BM;
    const int bn = blockIdx.x * BN;
    const int tr = (tid >> 4) << 2;
    const int tc = (tid & 15) << 2;
    const int lr = tid >> 2;
    const int lc = (tid & 3) << 2;
    float acc[4][4] = {{0.f}};

    for (int k0 = 0; k0 < K; k0 += BKK) {
        float4 av = *(const float4*)(A  + (size_t)(bm + lr) * K + k0 + lc);
        float4 wv = *(const float4*)(Wt + (size_t)(bn + lr) * K + k0 + lc);
        As[lc + 0][lr] = av.x; As[lc + 1][lr] = av.y;
        As[lc + 2][lr] = av.z; As[lc + 3][lr] = av.w;
        Bs[lc + 0][lr] = wv.x; Bs[lc + 1][lr] = wv.y;
        Bs[lc + 2][lr] = wv.z; Bs[lc + 3][lr] = wv.w;
        __syncthreads();
#pragma unroll
        for (int kk = 0; kk < BKK; ++kk) {
            float4 a  = *(const float4*)&As[kk][tr];
            float4 bq = *(const float4*)&Bs[kk][tc];
            float av4[4] = {a.x, a.y, a.z, a.w};
            float bv4[4] = {bq.x, bq.y, bq.z, bq.w};
#pragma unroll
            for (int ii = 0; ii < 4; ++ii)
#pragma unroll
                for (int jj = 0; jj < 4; ++jj)
                    acc[ii][jj] = fmaf(av4[ii], bv4[jj], acc[ii][jj]);
        }
        __syncthreads();
    }
#pragma unroll
    for (int ii = 0; ii < 4; ++ii) {
        int m = bm + tr + ii;
#pragma unroll
        for (int jj = 0; jj < 4; ++jj) {
            int nn = bn + tc + jj;
            float v = acc[ii][jj] + bias[nn];
            if (act == 1) v = 0.5f * v * (1.0f + erff(v * 0.70710678118654752f));
            Cmat[(size_t)m * N + nn] = v;
        }
    }
}

// L2-normalize first 256 channels of each row, per 32-channel head group
__global__ __launch_bounds__(256) void headnorm(float* __restrict__ buf, int rowStride)
{
    size_t row = blockIdx.x;
    int tid = threadIdx.x;
    float* p = buf + row * (size_t)rowStride + tid;
    float v = *p;
    float ss = v * v;
#pragma unroll
    for (int off = 16; off; off >>= 1) ss += __shfl_xor(ss, off, 32);
    *p = v / fmaxf(sqrtf(ss), 1e-12f);
}

// 8x8 average pool of x_sr (B,N,C) + LayerNorm -> xpool (B,64,C)
__global__ __launch_bounds__(256) void pool_ln(
    const float* __restrict__ xsr, const float* __restrict__ g,
    const float* __restrict__ be, float* __restrict__ xpool, int Hh, int Ww)
{
    const int C = 256;
    const int Nn = Hh * Ww;
    int b = blockIdx.x >> 6;
    int pidx = blockIdx.x & 63;
    int ph = pidx >> 3, pw = pidx & 7;
    int tid = threadIdx.x;
    float s = 0.f;
    for (int si = 0; si < 8; ++si) {
        int i = ph * 8 + si;
        const float* rowp = xsr + ((size_t)b * Nn + (size_t)i * Ww + pw * 8) * C + tid;
#pragma unroll
        for (int sj = 0; sj < 8; ++sj) s += rowp[(size_t)sj * C];
    }
    s *= (1.f / 64.f);
    __shared__ float red[256];
    red[tid] = s; __syncthreads();
    for (int st = 128; st; st >>= 1) { if (tid < st) red[tid] += red[tid + st]; __syncthreads(); }
    float mean = red[0] * (1.f / 256.f);
    __syncthreads();
    float dv = s - mean;
    red[tid] = dv * dv; __syncthreads();
    for (int st = 128; st; st >>= 1) { if (tid < st) red[tid] += red[tid + st]; __syncthreads(); }
    float var = red[0] * (1.f / 256.f);
    xpool[(size_t)blockIdx.x * C + tid] = dv * rsqrtf(var + 1e-5f) * g[tid] + be[tid];
}

// cpb = relu(table @ fc1^T + b1) @ fc2^T + b2
__global__ __launch_bounds__(256) void cpb_mlp(
    const float* __restrict__ table, const float* __restrict__ w1,
    const float* __restrict__ b1, const float* __restrict__ w2,
    const float* __restrict__ b2, float* __restrict__ outc)
{
    int row = blockIdx.x;
    float t0 = table[(size_t)row * 2], t1 = table[(size_t)row * 2 + 1];
    int tid = threadIdx.x;
    int tid2 = tid + 256;
    float h0 = fmaxf(fmaf(t1, w1[tid * 2 + 1],  fmaf(t0, w1[tid * 2],  b1[tid])),  0.f);
    float h1 = fmaxf(fmaf(t1, w1[tid2 * 2 + 1], fmaf(t0, w1[tid2 * 2], b1[tid2])), 0.f);
    __shared__ float red[256];
    for (int hh = 0; hh < 8; ++hh) {
        red[tid] = h0 * w2[hh * 512 + tid] + h1 * w2[hh * 512 + tid2];
        __syncthreads();
        for (int st = 128; st; st >>= 1) { if (tid < st) red[tid] += red[tid + st]; __syncthreads(); }
        if (tid == 0) outc[(size_t)row * 8 + hh] = red[0] + b2[hh];
        __syncthreads();
    }
}

// ---------------------------------------------------------------------------
// attn_v3: one lane = one query. Block = 4 waves = 4 image rows of one (b,h).
// Barrier-free after staging: all scores/softmax/AV in-lane.
// ---------------------------------------------------------------------------
__global__ __launch_bounds__(256) void attn_v3(
    const float* __restrict__ qraw, // (B,N,256) raw q (pre-norm)
    const float* __restrict__ kv,   // (B,N,512) k normed | v
    const float* __restrict__ kvp,  // (B,64,512) k_pool normed | v_pool
    const float* __restrict__ cpbT, // (T,8)
    const int*   __restrict__ rpi,  // (N,64)
    const float* __restrict__ sls,  // (N)
    const float* __restrict__ temp, // (8)
    const float* __restrict__ qe,   // (8,32)
    const float* __restrict__ rbl,  // (8,9)
    const float* __restrict__ ltok, // (8,32,9)
    const float* __restrict__ lbias,// (8,9)
    ushort_t* __restrict__ attno_bf)// (B,N,256) bf16
{
    const int h = blockIdx.y, b = blockIdx.z;
    const int t = threadIdx.x;

    __shared__ float kp_s[64][36];
    __shared__ float vp_s[64][36];
    __shared__ float lts[9][32];     // ltok[h] transposed: [l][d]
    __shared__ float rbl_s[9], lb_s[9], qe_s[32];

    {   // stage pool K/V (+small tables)
        const int p = t & 63, half = t >> 6;
        const float* g = kvp + ((size_t)(b * 64 + p)) * 512 + h * 32 + half * 8;
        *(float4*)&kp_s[p][half * 8 + 0] = *(const float4*)(g + 0);
        *(float4*)&kp_s[p][half * 8 + 4] = *(const float4*)(g + 4);
        *(float4*)&vp_s[p][half * 8 + 0] = *(const float4*)(g + 256);
        *(float4*)&vp_s[p][half * 8 + 4] = *(const float4*)(g + 260);
        // FIX(round 5): cover all 288 elements (t only spans 0..255; round-4
        // version left 256..287 unstaged -> garbage LDS -> absmax 0.30).
        for (int u = t; u < 288; u += 256) lts[u % 9][u / 9] = ltok[h * 288 + u];
        if (t < 9)  { rbl_s[t] = rbl[h * 9 + t]; lb_s[t] = lbias[h * 9 + t]; }
        if (t >= 64 && t < 96) qe_s[t - 64] = qe[h * 32 + (t - 64)];
    }
    __syncthreads();

    const int i = blockIdx.x * 4 + (t >> 6);   // image row
    const int j = t & 63;                      // query column = lane
    const int n = i * 64 + j;
    const size_t gq = (size_t)b * 4096 + n;

    const float tm = temp[h];
    const float sp = (tm > 20.f) ? tm : log1pf(expf(tm));

    // ---- load raw q, L2-normalize in-lane ----
    float qn_[32];
    {
        float ss = 0.f;
        const float4* qp = (const float4*)(qraw + gq * 256 + h * 32);
#pragma unroll
        for (int c = 0; c < 8; ++c) {
            float4 v = qp[c];
            qn_[4*c+0] = v.x; qn_[4*c+1] = v.y; qn_[4*c+2] = v.z; qn_[4*c+3] = v.w;
            ss += v.x*v.x + v.y*v.y + v.z*v.z + v.w*v.w;
        }
        const float invn = 1.0f / fmaxf(sqrtf(ss), 1e-12f);
#pragma unroll
        for (int d = 0; d < 32; ++d) qn_[d] *= invn;
    }

    // ---- learnable-token dots ----
    float lt[9];
#pragma unroll
    for (int l = 0; l < 9; ++l) {
        float dl = 0.f;
        const float4* lw = (const float4*)&lts[l][0];
#pragma unroll
        for (int c = 0; c < 8; ++c) {
            float4 w4 = lw[c];
            dl += qn_[4*c+0]*w4.x + qn_[4*c+1]*w4.y + qn_[4*c+2]*w4.z + qn_[4*c+3]*w4.w;
        }
        lt[l] = dl + lb_s[l];
    }

    // ---- scaled q ----
    const float scal = sp * sls[n];
    float qs_[32];
#pragma unroll
    for (int d = 0; d < 32; ++d) qs_[d] = (qn_[d] + qe_s[d]) * scal;

    // ---- pool scores (64, in registers; LDS reads wave-uniform) ----
    float s[64];
#pragma unroll
    for (int p = 0; p < 64; ++p) {
        const float4* kr = (const float4*)&kp_s[p][0];
        float acc = 0.f;
#pragma unroll
        for (int c = 0; c < 8; ++c) {
            float4 k4 = kr[c];
            acc += qs_[4*c+0]*k4.x + qs_[4*c+1]*k4.y + qs_[4*c+2]*k4.z + qs_[4*c+3]*k4.w;
        }
        const int idx = rpi[(size_t)n * 64 + p];
        s[p] = acc + cpbT[(size_t)idx * 8 + h];
    }

    // ---- local scores (9 taps; lane-adjacent global reads) ----
    float sl[9];
#pragma unroll
    for (int l = 0; l < 9; ++l) {
        const int di = l / 3 - 1, dj = l % 3 - 1;
        const int ii = i + di;
        const int jn = j + dj;
        const bool ok = (ii >= 0) && (ii < 64) && (jn >= 0) && (jn < 64);
        const int ic = max(min(ii, 63), 0);
        const int jc = max(min(jn, 63), 0);
        const float4* kr = (const float4*)(kv + ((size_t)(b * 4096 + ic * 64 + jc)) * 512 + h * 32);
        float dk = 0.f;
#pragma unroll
        for (int c = 0; c < 8; ++c) {
            float4 k4 = kr[c];
            dk += qs_[4*c+0]*k4.x + qs_[4*c+1]*k4.y + qs_[4*c+2]*k4.z + qs_[4*c+3]*k4.w;
        }
        sl[l] = ok ? (dk + rbl_s[l]) : -INFINITY;
    }

    // ---- softmax over 73, fully in-lane ----
    float m = s[0];
#pragma unroll
    for (int p = 1; p < 64; ++p) m = fmaxf(m, s[p]);
#pragma unroll
    for (int l = 0; l < 9; ++l) m = fmaxf(m, sl[l]);
    float Z = 0.f;
#pragma unroll
    for (int p = 0; p < 64; ++p) { s[p] = __expf(s[p] - m); Z += s[p]; }
#pragma unroll
    for (int l = 0; l < 9; ++l) { sl[l] = __expf(sl[l] - m); Z += sl[l]; }
    const float invZ = 1.0f / Z;

    // ---- pool AV ----
    float o[32];
#pragma unroll
    for (int d = 0; d < 32; ++d) o[d] = 0.f;
#pragma unroll
    for (int p = 0; p < 64; ++p) {
        const float a = s[p] * invZ;
        const float4* vr = (const float4*)&vp_s[p][0];
#pragma unroll
        for (int c = 0; c < 8; ++c) {
            float4 v4 = vr[c];
            o[4*c+0] += a * v4.x; o[4*c+1] += a * v4.y;
            o[4*c+2] += a * v4.z; o[4*c+3] += a * v4.w;
        }
    }

    // ---- local AV (coef = a_local + lt; zero at OOB since v is zero-pad) ----
#pragma unroll
    for (int l = 0; l < 9; ++l) {
        const int di = l / 3 - 1, dj = l % 3 - 1;
        const int ii = i + di;
        const int jn = j + dj;
        const bool ok = (ii >= 0) && (ii < 64) && (jn >= 0) && (jn < 64);
        const int ic = max(min(ii, 63), 0);
        const int jc = max(min(jn, 63), 0);
        const float coef = ok ? (sl[l] * invZ + lt[l]) : 0.f;
        const float4* vr = (const float4*)(kv + ((size_t)(b * 4096 + ic * 64 + jc)) * 512 + 256 + h * 32);
#pragma unroll
        for (int c = 0; c < 8; ++c) {
            float4 v4 = vr[c];
            o[4*c+0] += coef * v4.x; o[4*c+1] += coef * v4.y;
            o[4*c+2] += coef * v4.z; o[4*c+3] += coef * v4.w;
        }
    }

    // ---- store bf16 ----
    ushort4* outp = (ushort4*)(attno_bf + gq * 256 + h * 32);
#pragma unroll
    for (int c = 0; c < 8; ++c) {
        ushort4 u;
        u.x = f2bf(o[4*c+0]); u.y = f2bf(o[4*c+1]);
        u.z = f2bf(o[4*c+2]); u.w = f2bf(o[4*c+3]);
        outp[c] = u;
    }
}

extern "C" void kernel_launch(void* const* d_in, const int* in_sizes, int n_in,
                              void* d_out, int out_size, void* d_ws, size_t ws_size,
                              hipStream_t stream)
{
    const float* x    = (const float*)d_in[0];
    const float* tbl  = (const float*)d_in[1];
    const float* sls  = (const float*)d_in[2];
    const float* q_w  = (const float*)d_in[3];
    const float* q_b  = (const float*)d_in[4];
    const float* kv_w = (const float*)d_in[5];
    const float* kv_b = (const float*)d_in[6];
    const float* temp = (const float*)d_in[7];
    const float* qe   = (const float*)d_in[8];
    const float* sr_w = (const float*)d_in[9];
    const float* sr_b = (const float*)d_in[10];
    const float* ng   = (const float*)d_in[11];
    const float* nb   = (const float*)d_in[12];
    const float* f1w  = (const float*)d_in[13];
    const float* f1b  = (const float*)d_in[14];
    const float* f2w  = (const float*)d_in[15];
    const float* f2b  = (const float*)d_in[16];
    const float* rbl  = (const float*)d_in[17];
    const float* ltok = (const float*)d_in[18];
    const float* lbias= (const float*)d_in[19];
    const float* pw   = (const float*)d_in[20];
    const float* pb   = (const float*)d_in[21];
    const int*   rpi  = (const int*)d_in[22];

    const int C = 256, Hh = 64, Ww = 64, Nn = Hh * Ww;
    const int B = in_sizes[0] / (Nn * C);   // 4
    const int T = in_sizes[1] / 2;
    const int M = B * Nn;                   // 16384

    float* ws = (float*)d_ws;
    size_t o = 0;
    float* qbuf  = ws + o; o += (size_t)M * C;
    float* kvbuf = ws + o; o += (size_t)M * 2 * C;
    float* xsr   = ws + o; o += (size_t)M * C;
    float* xpool = ws + o; o += (size_t)B * 64 * C;
    float* kvp   = ws + o; o += (size_t)B * 64 * 2 * C;
    float* cpbB  = ws + o; o += (size_t)T * 8;
    ushort_t* xhi = (ushort_t*)(ws + o); o += (size_t)M * C / 2;   // reused as attno_bf
    ushort_t* xlo = (ushort_t*)(ws + o); o += (size_t)M * C / 2;
    ushort_t* Wqkh = (ushort_t*)(ws + o); o += 512 * 256 / 2;
    ushort_t* Wqkl = (ushort_t*)(ws + o); o += 512 * 256 / 2;
    ushort_t* Wvs  = (ushort_t*)(ws + o); o += 512 * 256 / 2;
    ushort_t* Pwbf = (ushort_t*)(ws + o); o += 256 * 256 / 2;
    float* bqk = ws + o; o += 512;
    float* bvs = ws + o; o += 512;
    ushort_t* attno_bf = xhi;   // xhi dead after the two x-GEMMs

    dim3 blk(256);
    const int n4x = M * C / 4;

    // prepack
    cast_split<<<(n4x + 255) / 256, blk, 0, stream>>>((const float4*)x, (ushort4*)xhi, (ushort4*)xlo, n4x);
    pack_weights<<<512, blk, 0, stream>>>(q_w, kv_w, sr_w, pw, q_b, kv_b, sr_b,
                                          Wqkh, Wqkl, Wvs, Pwbf, bqk, bvs);
    // [q | k] split-precision GEMM; [v | sr] plain GEMM
    mfma_gemm<true ><<<dim3(4, M / 128), blk, 0, stream>>>(xhi, xlo, Wqkh, Wqkl, bqk, qbuf, kvbuf, 0);
    mfma_gemm<false><<<dim3(4, M / 128), blk, 0, stream>>>(xhi, xlo, Wvs,  Wvs,  bvs, kvbuf, xsr, 1);
    // normalize k (q is normalized in-lane inside attn_v3)
    headnorm<<<M, blk, 0, stream>>>(kvbuf, 2 * C);
    // pool + LN -> kv_p (fp32 GEMM, tiny) -> normalize k_pool
    pool_ln<<<B * 64, blk, 0, stream>>>(xsr, ng, nb, xpool, Hh, Ww);
    gemm_bias_act<<<dim3(2 * C / BN, (B * 64) / BM), blk, 0, stream>>>(xpool, kv_w, kv_b, kvp, B * 64, 2 * C, C, 0);
    headnorm<<<B * 64, blk, 0, stream>>>(kvp, 2 * C);
    // cpb
    cpb_mlp<<<T, blk, 0, stream>>>(tbl, f1w, f1b, f2w, f2b, cpbB);
    // attention (writes bf16 directly)
    attn_v3<<<dim3(16, 8, B), blk, 0, stream>>>(
        qbuf, kvbuf, kvp, cpbB, rpi, sls, temp, qe, rbl, ltok, lbias, attno_bf);
    // proj (plain bf16 MFMA)
    mfma_gemm<false><<<dim3(2, M / 128), blk, 0, stream>>>(attno_bf, attno_bf, Pwbf, Pwbf, pb, (float*)d_out, (float*)d_out, 2);
}

// Round 6
// 736.126 us; speedup vs baseline: 1.3948x; 1.3948x over previous
//
#include <hip/hip_runtime.h>
#include <math.h>

// ---------------------------------------------------------------------------
// TransNeXt aggregated attention. Round 6: attn_v4 — per-lane attention with
// flash-style chunked online softmax (kills the s[64] register array that
// spilled to scratch in round 5: VGPR 256, 1.07 GB scratch writes, 745 us).
// B=4, H=W=64, C=256, NH=8, hd=32, LOCAL_LEN=9, pool 8x8=64
// ---------------------------------------------------------------------------

typedef unsigned short ushort_t;
typedef __attribute__((ext_vector_type(8))) short short8;
typedef __attribute__((ext_vector_type(4))) float f32x4;

static __device__ __forceinline__ unsigned short f2bf(float f) {
    unsigned int u = __float_as_uint(f);
    unsigned int lsb = (u >> 16) & 1u;
    u += 0x7fffu + lsb;                 // round-to-nearest-even
    return (unsigned short)(u >> 16);
}
static __device__ __forceinline__ float bf2f(unsigned short h) {
    return __uint_as_float(((unsigned int)h) << 16);
}

#define GLOAD16(g, l)                                                        \
    __builtin_amdgcn_global_load_lds(                                        \
        (const __attribute__((address_space(1))) unsigned int*)(g),          \
        (__attribute__((address_space(3))) unsigned int*)(l), 16, 0, 0)

// ---------------------------------------------------------------------------
// MFMA GEMM: C = A @ W^T + bias. 128x128 tile, BK=32. (unchanged)
// ---------------------------------------------------------------------------
template <bool SPLIT>
__global__ __launch_bounds__(256) void mfma_gemm(
    const ushort_t* __restrict__ Ahi_g, const ushort_t* __restrict__ Alo_g,
    const ushort_t* __restrict__ Bhi_g, const ushort_t* __restrict__ Blo_g,
    const float* __restrict__ bias, float* __restrict__ out0,
    float* __restrict__ out1, int mode)
{
    const int K = 256;
    __shared__ ushort_t Ah[128 * 32];
    __shared__ ushort_t Bh[128 * 32];
    __shared__ ushort_t Al[SPLIT ? 128 * 32 : 8];
    __shared__ ushort_t Bl[SPLIT ? 128 * 32 : 8];

    const int t = threadIdx.x;
    const int w = t >> 6;
    const int lane = t & 63;
    const int bm = blockIdx.y * 128;
    const int bn = blockIdx.x * 128;
    const int wm = (w >> 1) * 64;
    const int wn = (w & 1) * 64;

    f32x4 acc[4][4];
#pragma unroll
    for (int i = 0; i < 4; ++i)
#pragma unroll
        for (int j = 0; j < 4; ++j) acc[i][j] = f32x4{0.f, 0.f, 0.f, 0.f};

    const int lrow = lane >> 2;
    const int lk8  = (lane & 3) * 8;

    for (int k0 = 0; k0 < K; k0 += 32) {
#pragma unroll
        for (int r = 0; r < 2; ++r) {
            const int rowoff = r * 64 + w * 16;
            const int arow = bm + rowoff + lrow;
            const int brow = bn + rowoff + lrow;
            const unsigned ldsoff = (unsigned)rowoff * 32;
            GLOAD16(Ahi_g + (size_t)arow * K + k0 + lk8, &Ah[ldsoff]);
            GLOAD16(Bhi_g + (size_t)brow * K + k0 + lk8, &Bh[ldsoff]);
            if (SPLIT) {
                GLOAD16(Alo_g + (size_t)arow * K + k0 + lk8, &Al[ldsoff]);
                GLOAD16(Blo_g + (size_t)brow * K + k0 + lk8, &Bl[ldsoff]);
            }
        }
        __syncthreads();

        const int fr = lane & 15;
        const int fq = (lane >> 4) * 8;
        short8 ah[4], bh[4], al[4], bl[4];
#pragma unroll
        for (int i = 0; i < 4; ++i) {
            ah[i] = *(const short8*)&Ah[(wm + i * 16 + fr) * 32 + fq];
            if (SPLIT) al[i] = *(const short8*)&Al[(wm + i * 16 + fr) * 32 + fq];
        }
#pragma unroll
        for (int j = 0; j < 4; ++j) {
            bh[j] = *(const short8*)&Bh[(wn + j * 16 + fr) * 32 + fq];
            if (SPLIT) bl[j] = *(const short8*)&Bl[(wn + j * 16 + fr) * 32 + fq];
        }
#pragma unroll
        for (int i = 0; i < 4; ++i)
#pragma unroll
            for (int j = 0; j < 4; ++j) {
                acc[i][j] = __builtin_amdgcn_mfma_f32_16x16x32_bf16(ah[i], bh[j], acc[i][j], 0, 0, 0);
                if (SPLIT) {
                    acc[i][j] = __builtin_amdgcn_mfma_f32_16x16x32_bf16(ah[i], bl[j], acc[i][j], 0, 0, 0);
                    acc[i][j] = __builtin_amdgcn_mfma_f32_16x16x32_bf16(al[i], bh[j], acc[i][j], 0, 0, 0);
                }
            }
        __syncthreads();
    }

    const int fr = lane & 15;
    const int q4 = (lane >> 4) * 4;
#pragma unroll
    for (int i = 0; i < 4; ++i) {
#pragma unroll
        for (int j = 0; j < 4; ++j) {
            const int col = bn + wn + j * 16 + fr;
            const float bv = bias[col];
#pragma unroll
            for (int r = 0; r < 4; ++r) {
                const int row = bm + wm + i * 16 + q4 + r;
                float v = acc[i][j][r] + bv;
                if (mode == 0) {
                    if (col < 256) out0[(size_t)row * 256 + col] = v;
                    else           out1[(size_t)row * 512 + (col - 256)] = v;
                } else if (mode == 1) {
                    if (col < 256) out0[(size_t)row * 512 + 256 + col] = v;
                    else {
                        v = 0.5f * v * (1.0f + erff(v * 0.70710678118654752f));
                        out1[(size_t)row * 256 + (col - 256)] = v;
                    }
                } else {
                    out0[(size_t)row * 256 + col] = v;
                }
            }
        }
    }
}

// x (fp32) -> hi/lo bf16 pair
__global__ __launch_bounds__(256) void cast_split(
    const float4* __restrict__ x, ushort4* __restrict__ hi,
    ushort4* __restrict__ lo, int n4)
{
    int i = blockIdx.x * 256 + threadIdx.x;
    if (i >= n4) return;
    float4 v = x[i];
    ushort4 h, l;
    h.x = f2bf(v.x); l.x = f2bf(v.x - bf2f(h.x));
    h.y = f2bf(v.y); l.y = f2bf(v.y - bf2f(h.y));
    h.z = f2bf(v.z); l.z = f2bf(v.z - bf2f(h.z));
    h.w = f2bf(v.w); l.w = f2bf(v.w - bf2f(h.w));
    hi[i] = h; lo[i] = l;
}

// Build packed weight/bias buffers.
__global__ __launch_bounds__(256) void pack_weights(
    const float* __restrict__ qw, const float* __restrict__ kvw,
    const float* __restrict__ srw, const float* __restrict__ pw,
    const float* __restrict__ qb, const float* __restrict__ kvb,
    const float* __restrict__ srb,
    ushort_t* __restrict__ Wqkh, ushort_t* __restrict__ Wqkl,
    ushort_t* __restrict__ Wvs, ushort_t* __restrict__ Pw,
    float* __restrict__ bqk, float* __restrict__ bvs)
{
    int idx = blockIdx.x * 256 + threadIdx.x;
    if (idx < 131072) {
        int nn = idx >> 8, k = idx & 255;
        float a = (nn < 256) ? qw[nn * 256 + k] : kvw[(nn - 256) * 256 + k];
        unsigned short h = f2bf(a);
        Wqkh[idx] = h;
        Wqkl[idx] = f2bf(a - bf2f(h));
        float b = (nn < 256) ? kvw[(nn + 256) * 256 + k] : srw[(nn - 256) * 256 + k];
        Wvs[idx] = f2bf(b);
    }
    if (idx < 65536) Pw[idx] = f2bf(pw[idx]);
    if (idx < 512) bqk[idx] = (idx < 256) ? qb[idx] : kvb[idx - 256];
    else if (idx < 1024) {
        int r = idx - 512;
        bvs[r] = (r < 256) ? kvb[r + 256] : srb[r - 256];
    }
}

// ------------------------- fp32 tile GEMM (kv_p only) -----------------------
#define BM 64
#define BN 64
#define BKK 16
__global__ __launch_bounds__(256) void gemm_bias_act(
    const float* __restrict__ A, const float* __restrict__ Wt,
    const float* __restrict__ bias, float* __restrict__ Cmat,
    int M, int N, int K, int act)
{
    __shared__ float As[BKK][BM + 4];
    __shared__ float Bs[BKK][BN + 4];
    const int tid = threadIdx.x;
    const int bm = blockIdx.y * BM;
    const int bn = blockIdx.x * BN;
    const int tr = (tid >> 4) << 2;
    const int tc = (tid & 15) << 2;
    const int lr = tid >> 2;
    const int lc = (tid & 3) << 2;
    float acc[4][4] = {{0.f}};

    for (int k0 = 0; k0 < K; k0 += BKK) {
        float4 av = *(const float4*)(A  + (size_t)(bm + lr) * K + k0 + lc);
        float4 wv = *(const float4*)(Wt + (size_t)(bn + lr) * K + k0 + lc);
        As[lc + 0][lr] = av.x; As[lc + 1][lr] = av.y;
        As[lc + 2][lr] = av.z; As[lc + 3][lr] = av.w;
        Bs[lc + 0][lr] = wv.x; Bs[lc + 1][lr] = wv.y;
        Bs[lc + 2][lr] = wv.z; Bs[lc + 3][lr] = wv.w;
        __syncthreads();
#pragma unroll
        for (int kk = 0; kk < BKK; ++kk) {
            float4 a  = *(const float4*)&As[kk][tr];
            float4 bq = *(const float4*)&Bs[kk][tc];
            float av4[4] = {a.x, a.y, a.z, a.w};
            float bv4[4] = {bq.x, bq.y, bq.z, bq.w};
#pragma unroll
            for (int ii = 0; ii < 4; ++ii)
#pragma unroll
                for (int jj = 0; jj < 4; ++jj)
                    acc[ii][jj] = fmaf(av4[ii], bv4[jj], acc[ii][jj]);
        }
        __syncthreads();
    }
#pragma unroll
    for (int ii = 0; ii < 4; ++ii) {
        int m = bm + tr + ii;
#pragma unroll
        for (int jj = 0; jj < 4; ++jj) {
            int nn = bn + tc + jj;
            float v = acc[ii][jj] + bias[nn];
            if (act == 1) v = 0.5f * v * (1.0f + erff(v * 0.70710678118654752f));
            Cmat[(size_t)m * N + nn] = v;
        }
    }
}

// L2-normalize first 256 channels of each row, per 32-channel head group
__global__ __launch_bounds__(256) void headnorm(float* __restrict__ buf, int rowStride)
{
    size_t row = blockIdx.x;
    int tid = threadIdx.x;
    float* p = buf + row * (size_t)rowStride + tid;
    float v = *p;
    float ss = v * v;
#pragma unroll
    for (int off = 16; off; off >>= 1) ss += __shfl_xor(ss, off, 32);
    *p = v / fmaxf(sqrtf(ss), 1e-12f);
}

// 8x8 average pool of x_sr (B,N,C) + LayerNorm -> xpool (B,64,C)
__global__ __launch_bounds__(256) void pool_ln(
    const float* __restrict__ xsr, const float* __restrict__ g,
    const float* __restrict__ be, float* __restrict__ xpool, int Hh, int Ww)
{
    const int C = 256;
    const int Nn = Hh * Ww;
    int b = blockIdx.x >> 6;
    int pidx = blockIdx.x & 63;
    int ph = pidx >> 3, pw = pidx & 7;
    int tid = threadIdx.x;
    float s = 0.f;
    for (int si = 0; si < 8; ++si) {
        int i = ph * 8 + si;
        const float* rowp = xsr + ((size_t)b * Nn + (size_t)i * Ww + pw * 8) * C + tid;
#pragma unroll
        for (int sj = 0; sj < 8; ++sj) s += rowp[(size_t)sj * C];
    }
    s *= (1.f / 64.f);
    __shared__ float red[256];
    red[tid] = s; __syncthreads();
    for (int st = 128; st; st >>= 1) { if (tid < st) red[tid] += red[tid + st]; __syncthreads(); }
    float mean = red[0] * (1.f / 256.f);
    __syncthreads();
    float dv = s - mean;
    red[tid] = dv * dv; __syncthreads();
    for (int st = 128; st; st >>= 1) { if (tid < st) red[tid] += red[tid + st]; __syncthreads(); }
    float var = red[0] * (1.f / 256.f);
    xpool[(size_t)blockIdx.x * C + tid] = dv * rsqrtf(var + 1e-5f) * g[tid] + be[tid];
}

// cpb = relu(table @ fc1^T + b1) @ fc2^T + b2
__global__ __launch_bounds__(256) void cpb_mlp(
    const float* __restrict__ table, const float* __restrict__ w1,
    const float* __restrict__ b1, const float* __restrict__ w2,
    const float* __restrict__ b2, float* __restrict__ outc)
{
    int row = blockIdx.x;
    float t0 = table[(size_t)row * 2], t1 = table[(size_t)row * 2 + 1];
    int tid = threadIdx.x;
    int tid2 = tid + 256;
    float h0 = fmaxf(fmaf(t1, w1[tid * 2 + 1],  fmaf(t0, w1[tid * 2],  b1[tid])),  0.f);
    float h1 = fmaxf(fmaf(t1, w1[tid2 * 2 + 1], fmaf(t0, w1[tid2 * 2], b1[tid2])), 0.f);
    __shared__ float red[256];
    for (int hh = 0; hh < 8; ++hh) {
        red[tid] = h0 * w2[hh * 512 + tid] + h1 * w2[hh * 512 + tid2];
        __syncthreads();
        for (int st = 128; st; st >>= 1) { if (tid < st) red[tid] += red[tid + st]; __syncthreads(); }
        if (tid == 0) outc[(size_t)row * 8 + hh] = red[0] + b2[hh];
        __syncthreads();
    }
}

// ---------------------------------------------------------------------------
// attn_v4: one lane = one query; flash-style online softmax over the 64 pool
// tokens in 4 chunks of 16 (no s[64] array -> no spill). Local-tap scores
// kept raw in 9 regs, their exp applied at the end with the final max.
// Register peak ~120 floats; __launch_bounds__(256,3) caps at 168 VGPR.
// ---------------------------------------------------------------------------
__global__ __launch_bounds__(256, 3) void attn_v4(
    const float* __restrict__ qraw, // (B,N,256) raw q (pre-norm)
    const float* __restrict__ kv,   // (B,N,512) k normed | v
    const float* __restrict__ kvp,  // (B,64,512) k_pool normed | v_pool
    const float* __restrict__ cpbT, // (T,8)
    const int*   __restrict__ rpi,  // (N,64)
    const float* __restrict__ sls,  // (N)
    const float* __restrict__ temp, // (8)
    const float* __restrict__ qe,   // (8,32)
    const float* __restrict__ rbl,  // (8,9)
    const float* __restrict__ ltok, // (8,32,9)
    const float* __restrict__ lbias,// (8,9)
    ushort_t* __restrict__ attno_bf)// (B,N,256) bf16
{
    const int h = blockIdx.y, b = blockIdx.z;
    const int t = threadIdx.x;

    __shared__ float kp_s[64][36];
    __shared__ float vp_s[64][36];
    __shared__ float lts[9][32];     // ltok[h] transposed: [l][d]
    __shared__ float rbl_s[9], lb_s[9], qe_s[32];

    {   // stage pool K/V (+small tables)
        const int p = t & 63, half = t >> 6;
        const float* g = kvp + ((size_t)(b * 64 + p)) * 512 + h * 32 + half * 8;
        *(float4*)&kp_s[p][half * 8 + 0] = *(const float4*)(g + 0);
        *(float4*)&kp_s[p][half * 8 + 4] = *(const float4*)(g + 4);
        *(float4*)&vp_s[p][half * 8 + 0] = *(const float4*)(g + 256);
        *(float4*)&vp_s[p][half * 8 + 4] = *(const float4*)(g + 260);
        for (int u = t; u < 288; u += 256) lts[u % 9][u / 9] = ltok[h * 288 + u];
        if (t < 9)  { rbl_s[t] = rbl[h * 9 + t]; lb_s[t] = lbias[h * 9 + t]; }
        if (t >= 64 && t < 96) qe_s[t - 64] = qe[h * 32 + (t - 64)];
    }
    __syncthreads();

    const int i = blockIdx.x * 4 + (t >> 6);   // image row
    const int j = t & 63;                      // query column = lane
    const int n = i * 64 + j;
    const size_t gq = (size_t)b * 4096 + n;

    const float tm = temp[h];
    const float sp = (tm > 20.f) ? tm : log1pf(expf(tm));

    // ---- load raw q, L2-normalize in-lane (qn lives in qv[]) ----
    float qv[32];
    {
        float ss = 0.f;
        const float4* qp = (const float4*)(qraw + gq * 256 + h * 32);
#pragma unroll
        for (int c = 0; c < 8; ++c) {
            float4 v = qp[c];
            qv[4*c+0] = v.x; qv[4*c+1] = v.y; qv[4*c+2] = v.z; qv[4*c+3] = v.w;
            ss += v.x*v.x + v.y*v.y + v.z*v.z + v.w*v.w;
        }
        const float invn = 1.0f / fmaxf(sqrtf(ss), 1e-12f);
#pragma unroll
        for (int d = 0; d < 32; ++d) qv[d] *= invn;
    }

    // ---- learnable-token dots (need q_norm; then qv becomes scaled q) ----
    float lt[9];
#pragma unroll
    for (int l = 0; l < 9; ++l) {
        float dl = 0.f;
        const float4* lw = (const float4*)&lts[l][0];
#pragma unroll
        for (int c = 0; c < 8; ++c) {
            float4 w4 = lw[c];
            dl += qv[4*c+0]*w4.x + qv[4*c+1]*w4.y + qv[4*c+2]*w4.z + qv[4*c+3]*w4.w;
        }
        lt[l] = dl + lb_s[l];
    }

    // ---- qv := scaled q (q_norm dies here) ----
    const float scal = sp * sls[n];
#pragma unroll
    for (int d = 0; d < 32; ++d) qv[d] = (qv[d] + qe_s[d]) * scal;

    // ---- local scores (9 taps, raw; exp deferred to the end) ----
    float sl[9];
#pragma unroll
    for (int l = 0; l < 9; ++l) {
        const int di = l / 3 - 1, dj = l % 3 - 1;
        const int ii = i + di;
        const int jn = j + dj;
        const bool ok = (ii >= 0) && (ii < 64) && (jn >= 0) && (jn < 64);
        const int ic = max(min(ii, 63), 0);
        const int jc = max(min(jn, 63), 0);
        const float4* kr = (const float4*)(kv + ((size_t)(b * 4096 + ic * 64 + jc)) * 512 + h * 32);
        float dk = 0.f;
#pragma unroll
        for (int c = 0; c < 8; ++c) {
            float4 k4 = kr[c];
            dk += qv[4*c+0]*k4.x + qv[4*c+1]*k4.y + qv[4*c+2]*k4.z + qv[4*c+3]*k4.w;
        }
        sl[l] = ok ? (dk + rbl_s[l]) : -INFINITY;
    }

    // ---- init running max from local scores (center tap always valid) ----
    float m = sl[0];
#pragma unroll
    for (int l = 1; l < 9; ++l) m = fmaxf(m, sl[l]);

    // ---- pool tokens: 4 chunks of 16, online softmax + AV ----
    float o[32];
#pragma unroll
    for (int d = 0; d < 32; ++d) o[d] = 0.f;
    float Z = 0.f;

#pragma unroll
    for (int cch = 0; cch < 4; ++cch) {
        float s16[16];
#pragma unroll
        for (int k = 0; k < 16; ++k) {
            const int p = cch * 16 + k;
            const float4* kr = (const float4*)&kp_s[p][0];
            float acc = 0.f;
#pragma unroll
            for (int c = 0; c < 8; ++c) {
                float4 k4 = kr[c];
                acc += qv[4*c+0]*k4.x + qv[4*c+1]*k4.y + qv[4*c+2]*k4.z + qv[4*c+3]*k4.w;
            }
            const int idx = rpi[(size_t)n * 64 + p];
            s16[k] = acc + cpbT[(size_t)idx * 8 + h];
        }
        float cmax = s16[0];
#pragma unroll
        for (int k = 1; k < 16; ++k) cmax = fmaxf(cmax, s16[k]);
        const float m_new = fmaxf(m, cmax);
        const float factor = __expf(m - m_new);   // ==1 when no new max
        Z *= factor;
#pragma unroll
        for (int d = 0; d < 32; ++d) o[d] *= factor;
        m = m_new;
#pragma unroll
        for (int k = 0; k < 16; ++k) {
            const float a = __expf(s16[k] - m);
            Z += a;
            const float4* vr = (const float4*)&vp_s[cch * 16 + k][0];
#pragma unroll
            for (int c = 0; c < 8; ++c) {
                float4 v4 = vr[c];
                o[4*c+0] += a * v4.x; o[4*c+1] += a * v4.y;
                o[4*c+2] += a * v4.z; o[4*c+3] += a * v4.w;
            }
        }
    }

    // ---- finish softmax: add local exps (computed with final m) ----
    float el[9];
#pragma unroll
    for (int l = 0; l < 9; ++l) { el[l] = __expf(sl[l] - m); Z += el[l]; }
    const float invZ = 1.0f / Z;
#pragma unroll
    for (int d = 0; d < 32; ++d) o[d] *= invZ;

    // ---- local AV (coef = a_local + lt; zero at OOB since v is zero-pad) ----
#pragma unroll
    for (int l = 0; l < 9; ++l) {
        const int di = l / 3 - 1, dj = l % 3 - 1;
        const int ii = i + di;
        const int jn = j + dj;
        const bool ok = (ii >= 0) && (ii < 64) && (jn >= 0) && (jn < 64);
        const int ic = max(min(ii, 63), 0);
        const int jc = max(min(jn, 63), 0);
        const float coef = ok ? (el[l] * invZ + lt[l]) : 0.f;
        const float4* vr = (const float4*)(kv + ((size_t)(b * 4096 + ic * 64 + jc)) * 512 + 256 + h * 32);
#pragma unroll
        for (int c = 0; c < 8; ++c) {
            float4 v4 = vr[c];
            o[4*c+0] += coef * v4.x; o[4*c+1] += coef * v4.y;
            o[4*c+2] += coef * v4.z; o[4*c+3] += coef * v4.w;
        }
    }

    // ---- store bf16 ----
    ushort4* outp = (ushort4*)(attno_bf + gq * 256 + h * 32);
#pragma unroll
    for (int c = 0; c < 8; ++c) {
        ushort4 u;
        u.x = f2bf(o[4*c+0]); u.y = f2bf(o[4*c+1]);
        u.z = f2bf(o[4*c+2]); u.w = f2bf(o[4*c+3]);
        outp[c] = u;
    }
}

extern "C" void kernel_launch(void* const* d_in, const int* in_sizes, int n_in,
                              void* d_out, int out_size, void* d_ws, size_t ws_size,
                              hipStream_t stream)
{
    const float* x    = (const float*)d_in[0];
    const float* tbl  = (const float*)d_in[1];
    const float* sls  = (const float*)d_in[2];
    const float* q_w  = (const float*)d_in[3];
    const float* q_b  = (const float*)d_in[4];
    const float* kv_w = (const float*)d_in[5];
    const float* kv_b = (const float*)d_in[6];
    const float* temp = (const float*)d_in[7];
    const float* qe   = (const float*)d_in[8];
    const float* sr_w = (const float*)d_in[9];
    const float* sr_b = (const float*)d_in[10];
    const float* ng   = (const float*)d_in[11];
    const float* nb   = (const float*)d_in[12];
    const float* f1w  = (const float*)d_in[13];
    const float* f1b  = (const float*)d_in[14];
    const float* f2w  = (const float*)d_in[15];
    const float* f2b  = (const float*)d_in[16];
    const float* rbl  = (const float*)d_in[17];
    const float* ltok = (const float*)d_in[18];
    const float* lbias= (const float*)d_in[19];
    const float* pw   = (const float*)d_in[20];
    const float* pb   = (const float*)d_in[21];
    const int*   rpi  = (const int*)d_in[22];

    const int C = 256, Hh = 64, Ww = 64, Nn = Hh * Ww;
    const int B = in_sizes[0] / (Nn * C);   // 4
    const int T = in_sizes[1] / 2;
    const int M = B * Nn;                   // 16384

    float* ws = (float*)d_ws;
    size_t o = 0;
    float* qbuf  = ws + o; o += (size_t)M * C;
    float* kvbuf = ws + o; o += (size_t)M * 2 * C;
    float* xsr   = ws + o; o += (size_t)M * C;
    float* xpool = ws + o; o += (size_t)B * 64 * C;
    float* kvp   = ws + o; o += (size_t)B * 64 * 2 * C;
    float* cpbB  = ws + o; o += (size_t)T * 8;
    ushort_t* xhi = (ushort_t*)(ws + o); o += (size_t)M * C / 2;   // reused as attno_bf
    ushort_t* xlo = (ushort_t*)(ws + o); o += (size_t)M * C / 2;
    ushort_t* Wqkh = (ushort_t*)(ws + o); o += 512 * 256 / 2;
    ushort_t* Wqkl = (ushort_t*)(ws + o); o += 512 * 256 / 2;
    ushort_t* Wvs  = (ushort_t*)(ws + o); o += 512 * 256 / 2;
    ushort_t* Pwbf = (ushort_t*)(ws + o); o += 256 * 256 / 2;
    float* bqk = ws + o; o += 512;
    float* bvs = ws + o; o += 512;
    ushort_t* attno_bf = xhi;   // xhi dead after the two x-GEMMs

    dim3 blk(256);
    const int n4x = M * C / 4;

    // prepack
    cast_split<<<(n4x + 255) / 256, blk, 0, stream>>>((const float4*)x, (ushort4*)xhi, (ushort4*)xlo, n4x);
    pack_weights<<<512, blk, 0, stream>>>(q_w, kv_w, sr_w, pw, q_b, kv_b, sr_b,
                                          Wqkh, Wqkl, Wvs, Pwbf, bqk, bvs);
    // [q | k] split-precision GEMM; [v | sr] plain GEMM
    mfma_gemm<true ><<<dim3(4, M / 128), blk, 0, stream>>>(xhi, xlo, Wqkh, Wqkl, bqk, qbuf, kvbuf, 0);
    mfma_gemm<false><<<dim3(4, M / 128), blk, 0, stream>>>(xhi, xlo, Wvs,  Wvs,  bvs, kvbuf, xsr, 1);
    // normalize k (q is normalized in-lane inside attn_v4)
    headnorm<<<M, blk, 0, stream>>>(kvbuf, 2 * C);
    // pool + LN -> kv_p (fp32 GEMM, tiny) -> normalize k_pool
    pool_ln<<<B * 64, blk, 0, stream>>>(xsr, ng, nb, xpool, Hh, Ww);
    gemm_bias_act<<<dim3(2 * C / BN, (B * 64) / BM), blk, 0, stream>>>(xpool, kv_w, kv_b, kvp, B * 64, 2 * C, C, 0);
    headnorm<<<B * 64, blk, 0, stream>>>(kvp, 2 * C);
    // cpb
    cpb_mlp<<<T, blk, 0, stream>>>(tbl, f1w, f1b, f2w, f2b, cpbB);
    // attention (writes bf16 directly)
    attn_v4<<<dim3(16, 8, B), blk, 0, stream>>>(
        qbuf, kvbuf, kvp, cpbB, rpi, sls, temp, qe, rbl, ltok, lbias, attno_bf);
    // proj (plain bf16 MFMA)
    mfma_gemm<false><<<dim3(2, M / 128), blk, 0, stream>>>(attno_bf, attno_bf, Pwbf, Pwbf, pb, (float*)d_out, (float*)d_out, 2);
}

// Round 7
// 350.950 us; speedup vs baseline: 2.9257x; 2.0975x over previous
//
#include <hip/hip_runtime.h>
#include <math.h>

// ---------------------------------------------------------------------------
// TransNeXt aggregated attention. Round 7: attn_v5 — lane-pair-per-query
// attention. Round 6 spilled (compiler self-capped at 84 VGPR, 766 MB scratch
// writes); v5 halves the per-lane live set (~58 floats) via 16-channel
// partial dots + __shfl_xor(.,1) pair reduction. Online softmax in chunks
// of 8 over the 64 pool tokens.
// B=4, H=W=64, C=256, NH=8, hd=32, LOCAL_LEN=9, pool 8x8=64
// ---------------------------------------------------------------------------

typedef unsigned short ushort_t;
typedef __attribute__((ext_vector_type(8))) short short8;
typedef __attribute__((ext_vector_type(4))) float f32x4;

static __device__ __forceinline__ unsigned short f2bf(float f) {
    unsigned int u = __float_as_uint(f);
    unsigned int lsb = (u >> 16) & 1u;
    u += 0x7fffu + lsb;                 // round-to-nearest-even
    return (unsigned short)(u >> 16);
}
static __device__ __forceinline__ float bf2f(unsigned short h) {
    return __uint_as_float(((unsigned int)h) << 16);
}

#define GLOAD16(g, l)                                                        \
    __builtin_amdgcn_global_load_lds(                                        \
        (const __attribute__((address_space(1))) unsigned int*)(g),          \
        (__attribute__((address_space(3))) unsigned int*)(l), 16, 0, 0)

// ---------------------------------------------------------------------------
// MFMA GEMM: C = A @ W^T + bias. 128x128 tile, BK=32. (unchanged)
// ---------------------------------------------------------------------------
template <bool SPLIT>
__global__ __launch_bounds__(256) void mfma_gemm(
    const ushort_t* __restrict__ Ahi_g, const ushort_t* __restrict__ Alo_g,
    const ushort_t* __restrict__ Bhi_g, const ushort_t* __restrict__ Blo_g,
    const float* __restrict__ bias, float* __restrict__ out0,
    float* __restrict__ out1, int mode)
{
    const int K = 256;
    __shared__ ushort_t Ah[128 * 32];
    __shared__ ushort_t Bh[128 * 32];
    __shared__ ushort_t Al[SPLIT ? 128 * 32 : 8];
    __shared__ ushort_t Bl[SPLIT ? 128 * 32 : 8];

    const int t = threadIdx.x;
    const int w = t >> 6;
    const int lane = t & 63;
    const int bm = blockIdx.y * 128;
    const int bn = blockIdx.x * 128;
    const int wm = (w >> 1) * 64;
    const int wn = (w & 1) * 64;

    f32x4 acc[4][4];
#pragma unroll
    for (int i = 0; i < 4; ++i)
#pragma unroll
        for (int j = 0; j < 4; ++j) acc[i][j] = f32x4{0.f, 0.f, 0.f, 0.f};

    const int lrow = lane >> 2;
    const int lk8  = (lane & 3) * 8;

    for (int k0 = 0; k0 < K; k0 += 32) {
#pragma unroll
        for (int r = 0; r < 2; ++r) {
            const int rowoff = r * 64 + w * 16;
            const int arow = bm + rowoff + lrow;
            const int brow = bn + rowoff + lrow;
            const unsigned ldsoff = (unsigned)rowoff * 32;
            GLOAD16(Ahi_g + (size_t)arow * K + k0 + lk8, &Ah[ldsoff]);
            GLOAD16(Bhi_g + (size_t)brow * K + k0 + lk8, &Bh[ldsoff]);
            if (SPLIT) {
                GLOAD16(Alo_g + (size_t)arow * K + k0 + lk8, &Al[ldsoff]);
                GLOAD16(Blo_g + (size_t)brow * K + k0 + lk8, &Bl[ldsoff]);
            }
        }
        __syncthreads();

        const int fr = lane & 15;
        const int fq = (lane >> 4) * 8;
        short8 ah[4], bh[4], al[4], bl[4];
#pragma unroll
        for (int i = 0; i < 4; ++i) {
            ah[i] = *(const short8*)&Ah[(wm + i * 16 + fr) * 32 + fq];
            if (SPLIT) al[i] = *(const short8*)&Al[(wm + i * 16 + fr) * 32 + fq];
        }
#pragma unroll
        for (int j = 0; j < 4; ++j) {
            bh[j] = *(const short8*)&Bh[(wn + j * 16 + fr) * 32 + fq];
            if (SPLIT) bl[j] = *(const short8*)&Bl[(wn + j * 16 + fr) * 32 + fq];
        }
#pragma unroll
        for (int i = 0; i < 4; ++i)
#pragma unroll
            for (int j = 0; j < 4; ++j) {
                acc[i][j] = __builtin_amdgcn_mfma_f32_16x16x32_bf16(ah[i], bh[j], acc[i][j], 0, 0, 0);
                if (SPLIT) {
                    acc[i][j] = __builtin_amdgcn_mfma_f32_16x16x32_bf16(ah[i], bl[j], acc[i][j], 0, 0, 0);
                    acc[i][j] = __builtin_amdgcn_mfma_f32_16x16x32_bf16(al[i], bh[j], acc[i][j], 0, 0, 0);
                }
            }
        __syncthreads();
    }

    const int fr = lane & 15;
    const int q4 = (lane >> 4) * 4;
#pragma unroll
    for (int i = 0; i < 4; ++i) {
#pragma unroll
        for (int j = 0; j < 4; ++j) {
            const int col = bn + wn + j * 16 + fr;
            const float bv = bias[col];
#pragma unroll
            for (int r = 0; r < 4; ++r) {
                const int row = bm + wm + i * 16 + q4 + r;
                float v = acc[i][j][r] + bv;
                if (mode == 0) {
                    if (col < 256) out0[(size_t)row * 256 + col] = v;
                    else           out1[(size_t)row * 512 + (col - 256)] = v;
                } else if (mode == 1) {
                    if (col < 256) out0[(size_t)row * 512 + 256 + col] = v;
                    else {
                        v = 0.5f * v * (1.0f + erff(v * 0.70710678118654752f));
                        out1[(size_t)row * 256 + (col - 256)] = v;
                    }
                } else {
                    out0[(size_t)row * 256 + col] = v;
                }
            }
        }
    }
}

// x (fp32) -> hi/lo bf16 pair
__global__ __launch_bounds__(256) void cast_split(
    const float4* __restrict__ x, ushort4* __restrict__ hi,
    ushort4* __restrict__ lo, int n4)
{
    int i = blockIdx.x * 256 + threadIdx.x;
    if (i >= n4) return;
    float4 v = x[i];
    ushort4 h, l;
    h.x = f2bf(v.x); l.x = f2bf(v.x - bf2f(h.x));
    h.y = f2bf(v.y); l.y = f2bf(v.y - bf2f(h.y));
    h.z = f2bf(v.z); l.z = f2bf(v.z - bf2f(h.z));
    h.w = f2bf(v.w); l.w = f2bf(v.w - bf2f(h.w));
    hi[i] = h; lo[i] = l;
}

// Build packed weight/bias buffers.
__global__ __launch_bounds__(256) void pack_weights(
    const float* __restrict__ qw, const float* __restrict__ kvw,
    const float* __restrict__ srw, const float* __restrict__ pw,
    const float* __restrict__ qb, const float* __restrict__ kvb,
    const float* __restrict__ srb,
    ushort_t* __restrict__ Wqkh, ushort_t* __restrict__ Wqkl,
    ushort_t* __restrict__ Wvs, ushort_t* __restrict__ Pw,
    float* __restrict__ bqk, float* __restrict__ bvs)
{
    int idx = blockIdx.x * 256 + threadIdx.x;
    if (idx < 131072) {
        int nn = idx >> 8, k = idx & 255;
        float a = (nn < 256) ? qw[nn * 256 + k] : kvw[(nn - 256) * 256 + k];
        unsigned short h = f2bf(a);
        Wqkh[idx] = h;
        Wqkl[idx] = f2bf(a - bf2f(h));
        float b = (nn < 256) ? kvw[(nn + 256) * 256 + k] : srw[(nn - 256) * 256 + k];
        Wvs[idx] = f2bf(b);
    }
    if (idx < 65536) Pw[idx] = f2bf(pw[idx]);
    if (idx < 512) bqk[idx] = (idx < 256) ? qb[idx] : kvb[idx - 256];
    else if (idx < 1024) {
        int r = idx - 512;
        bvs[r] = (r < 256) ? kvb[r + 256] : srb[r - 256];
    }
}

// ------------------------- fp32 tile GEMM (kv_p only) -----------------------
#define BM 64
#define BN 64
#define BKK 16
__global__ __launch_bounds__(256) void gemm_bias_act(
    const float* __restrict__ A, const float* __restrict__ Wt,
    const float* __restrict__ bias, float* __restrict__ Cmat,
    int M, int N, int K, int act)
{
    __shared__ float As[BKK][BM + 4];
    __shared__ float Bs[BKK][BN + 4];
    const int tid = threadIdx.x;
    const int bm = blockIdx.y * BM;
    const int bn = blockIdx.x * BN;
    const int tr = (tid >> 4) << 2;
    const int tc = (tid & 15) << 2;
    const int lr = tid >> 2;
    const int lc = (tid & 3) << 2;
    float acc[4][4] = {{0.f}};

    for (int k0 = 0; k0 < K; k0 += BKK) {
        float4 av = *(const float4*)(A  + (size_t)(bm + lr) * K + k0 + lc);
        float4 wv = *(const float4*)(Wt + (size_t)(bn + lr) * K + k0 + lc);
        As[lc + 0][lr] = av.x; As[lc + 1][lr] = av.y;
        As[lc + 2][lr] = av.z; As[lc + 3][lr] = av.w;
        Bs[lc + 0][lr] = wv.x; Bs[lc + 1][lr] = wv.y;
        Bs[lc + 2][lr] = wv.z; Bs[lc + 3][lr] = wv.w;
        __syncthreads();
#pragma unroll
        for (int kk = 0; kk < BKK; ++kk) {
            float4 a  = *(const float4*)&As[kk][tr];
            float4 bq = *(const float4*)&Bs[kk][tc];
            float av4[4] = {a.x, a.y, a.z, a.w};
            float bv4[4] = {bq.x, bq.y, bq.z, bq.w};
#pragma unroll
            for (int ii = 0; ii < 4; ++ii)
#pragma unroll
                for (int jj = 0; jj < 4; ++jj)
                    acc[ii][jj] = fmaf(av4[ii], bv4[jj], acc[ii][jj]);
        }
        __syncthreads();
    }
#pragma unroll
    for (int ii = 0; ii < 4; ++ii) {
        int m = bm + tr + ii;
#pragma unroll
        for (int jj = 0; jj < 4; ++jj) {
            int nn = bn + tc + jj;
            float v = acc[ii][jj] + bias[nn];
            if (act == 1) v = 0.5f * v * (1.0f + erff(v * 0.70710678118654752f));
            Cmat[(size_t)m * N + nn] = v;
        }
    }
}

// L2-normalize first 256 channels of each row, per 32-channel head group
__global__ __launch_bounds__(256) void headnorm(float* __restrict__ buf, int rowStride)
{
    size_t row = blockIdx.x;
    int tid = threadIdx.x;
    float* p = buf + row * (size_t)rowStride + tid;
    float v = *p;
    float ss = v * v;
#pragma unroll
    for (int off = 16; off; off >>= 1) ss += __shfl_xor(ss, off, 32);
    *p = v / fmaxf(sqrtf(ss), 1e-12f);
}

// 8x8 average pool of x_sr (B,N,C) + LayerNorm -> xpool (B,64,C)
__global__ __launch_bounds__(256) void pool_ln(
    const float* __restrict__ xsr, const float* __restrict__ g,
    const float* __restrict__ be, float* __restrict__ xpool, int Hh, int Ww)
{
    const int C = 256;
    const int Nn = Hh * Ww;
    int b = blockIdx.x >> 6;
    int pidx = blockIdx.x & 63;
    int ph = pidx >> 3, pw = pidx & 7;
    int tid = threadIdx.x;
    float s = 0.f;
    for (int si = 0; si < 8; ++si) {
        int i = ph * 8 + si;
        const float* rowp = xsr + ((size_t)b * Nn + (size_t)i * Ww + pw * 8) * C + tid;
#pragma unroll
        for (int sj = 0; sj < 8; ++sj) s += rowp[(size_t)sj * C];
    }
    s *= (1.f / 64.f);
    __shared__ float red[256];
    red[tid] = s; __syncthreads();
    for (int st = 128; st; st >>= 1) { if (tid < st) red[tid] += red[tid + st]; __syncthreads(); }
    float mean = red[0] * (1.f / 256.f);
    __syncthreads();
    float dv = s - mean;
    red[tid] = dv * dv; __syncthreads();
    for (int st = 128; st; st >>= 1) { if (tid < st) red[tid] += red[tid + st]; __syncthreads(); }
    float var = red[0] * (1.f / 256.f);
    xpool[(size_t)blockIdx.x * C + tid] = dv * rsqrtf(var + 1e-5f) * g[tid] + be[tid];
}

// cpb = relu(table @ fc1^T + b1) @ fc2^T + b2
__global__ __launch_bounds__(256) void cpb_mlp(
    const float* __restrict__ table, const float* __restrict__ w1,
    const float* __restrict__ b1, const float* __restrict__ w2,
    const float* __restrict__ b2, float* __restrict__ outc)
{
    int row = blockIdx.x;
    float t0 = table[(size_t)row * 2], t1 = table[(size_t)row * 2 + 1];
    int tid = threadIdx.x;
    int tid2 = tid + 256;
    float h0 = fmaxf(fmaf(t1, w1[tid * 2 + 1],  fmaf(t0, w1[tid * 2],  b1[tid])),  0.f);
    float h1 = fmaxf(fmaf(t1, w1[tid2 * 2 + 1], fmaf(t0, w1[tid2 * 2], b1[tid2])), 0.f);
    __shared__ float red[256];
    for (int hh = 0; hh < 8; ++hh) {
        red[tid] = h0 * w2[hh * 512 + tid] + h1 * w2[hh * 512 + tid2];
        __syncthreads();
        for (int st = 128; st; st >>= 1) { if (tid < st) red[tid] += red[tid + st]; __syncthreads(); }
        if (tid == 0) outc[(size_t)row * 8 + hh] = red[0] + b2[hh];
        __syncthreads();
    }
}

// ---------------------------------------------------------------------------
// attn_v5: lane pair (2k, 2k+1) = one query; each lane owns 16 of 32 channels.
// All dots are 16-wide partials + __shfl_xor(.,1). Per-lane live set ~58
// floats -> no spill even at the compiler's 84-VGPR preference.
// Wave = 32 queries of one image row. Block = 4 waves = 128 queries.
// ---------------------------------------------------------------------------
__global__ __launch_bounds__(256) void attn_v5(
    const float* __restrict__ qraw, // (B,N,256) raw q (pre-norm)
    const float* __restrict__ kv,   // (B,N,512) k normed | v
    const float* __restrict__ kvp,  // (B,64,512) k_pool normed | v_pool
    const float* __restrict__ cpbT, // (T,8)
    const int*   __restrict__ rpi,  // (N,64)
    const float* __restrict__ sls,  // (N)
    const float* __restrict__ temp, // (8)
    const float* __restrict__ qe,   // (8,32)
    const float* __restrict__ rbl,  // (8,9)
    const float* __restrict__ ltok, // (8,32,9)
    const float* __restrict__ lbias,// (8,9)
    ushort_t* __restrict__ attno_bf)// (B,N,256) bf16
{
    const int h = blockIdx.y, b = blockIdx.z;
    const int t = threadIdx.x;

    __shared__ float kp_s[64][36];
    __shared__ float vp_s[64][36];
    __shared__ float lts[9][32];     // ltok[h] transposed: [l][d]
    __shared__ float rbl_s[9], lb_s[9], qe_s[32];

    {   // stage pool K/V (+small tables)
        const int p = t & 63, half = t >> 6;
        const float* g = kvp + ((size_t)(b * 64 + p)) * 512 + h * 32 + half * 8;
        *(float4*)&kp_s[p][half * 8 + 0] = *(const float4*)(g + 0);
        *(float4*)&kp_s[p][half * 8 + 4] = *(const float4*)(g + 4);
        *(float4*)&vp_s[p][half * 8 + 0] = *(const float4*)(g + 256);
        *(float4*)&vp_s[p][half * 8 + 4] = *(const float4*)(g + 260);
        for (int u = t; u < 288; u += 256) lts[u % 9][u / 9] = ltok[h * 288 + u];
        if (t < 9)  { rbl_s[t] = rbl[h * 9 + t]; lb_s[t] = lbias[h * 9 + t]; }
        if (t >= 64 && t < 96) qe_s[t - 64] = qe[h * 32 + (t - 64)];
    }
    __syncthreads();

    const int w = t >> 6;
    const int lane = t & 63;
    const int qi = lane >> 1;        // query within wave (0..31)
    const int c  = lane & 1;         // channel half
    const int co = c * 16;           // channel offset
    const int n = blockIdx.x * 128 + w * 32 + qi;
    const int i = n >> 6, j = n & 63;
    const size_t gq = (size_t)b * 4096 + n;

    const float tm = temp[h];
    const float sp = (tm > 20.f) ? tm : log1pf(expf(tm));

    // ---- load q half, L2-normalize (pair-reduced sum of squares) ----
    float qv[16];
    {
        float ss = 0.f;
        const float4* qp = (const float4*)(qraw + gq * 256 + h * 32 + co);
#pragma unroll
        for (int c4 = 0; c4 < 4; ++c4) {
            float4 v = qp[c4];
            qv[4*c4+0] = v.x; qv[4*c4+1] = v.y; qv[4*c4+2] = v.z; qv[4*c4+3] = v.w;
            ss += v.x*v.x + v.y*v.y + v.z*v.z + v.w*v.w;
        }
        ss += __shfl_xor(ss, 1);
        const float invn = 1.0f / fmaxf(sqrtf(ss), 1e-12f);
#pragma unroll
        for (int d = 0; d < 16; ++d) qv[d] *= invn;
    }

    // ---- learnable-token dots (q_norm; then qv becomes scaled q) ----
    float lt[9];
#pragma unroll
    for (int l = 0; l < 9; ++l) {
        float dl = 0.f;
        const float4* lw = (const float4*)&lts[l][co];
#pragma unroll
        for (int c4 = 0; c4 < 4; ++c4) {
            float4 w4 = lw[c4];
            dl += qv[4*c4+0]*w4.x + qv[4*c4+1]*w4.y + qv[4*c4+2]*w4.z + qv[4*c4+3]*w4.w;
        }
        dl += __shfl_xor(dl, 1);
        lt[l] = dl + lb_s[l];
    }

    // ---- qv := scaled q half ----
    const float scal = sp * sls[n];
#pragma unroll
    for (int d = 0; d < 16; ++d) qv[d] = (qv[d] + qe_s[co + d]) * scal;

    // ---- local scores (9 taps, raw; exp deferred) ----
    float sl[9];
#pragma unroll
    for (int l = 0; l < 9; ++l) {
        const int di = l / 3 - 1, dj = l % 3 - 1;
        const int ii = i + di;               // wave-uniform
        const int jn = j + dj;
        const bool ok = (ii >= 0) && (ii < 64) && (jn >= 0) && (jn < 64);
        const int ic = max(min(ii, 63), 0);
        const int jc = max(min(jn, 63), 0);
        const float4* kr = (const float4*)(kv + ((size_t)(b * 4096 + ic * 64 + jc)) * 512 + h * 32 + co);
        float dk = 0.f;
#pragma unroll
        for (int c4 = 0; c4 < 4; ++c4) {
            float4 k4 = kr[c4];
            dk += qv[4*c4+0]*k4.x + qv[4*c4+1]*k4.y + qv[4*c4+2]*k4.z + qv[4*c4+3]*k4.w;
        }
        dk += __shfl_xor(dk, 1);
        sl[l] = ok ? (dk + rbl_s[l]) : -INFINITY;
    }

    // ---- running max from local scores (center tap always valid) ----
    float m = sl[0];
#pragma unroll
    for (int l = 1; l < 9; ++l) m = fmaxf(m, sl[l]);

    // ---- pool tokens: 8 chunks of 8, online softmax + AV ----
    float o[16];
#pragma unroll
    for (int d = 0; d < 16; ++d) o[d] = 0.f;
    float Z = 0.f;

    for (int cch = 0; cch < 8; ++cch) {
        float s8[8];
#pragma unroll
        for (int k = 0; k < 8; ++k) {
            const int p = cch * 8 + k;
            const float4* kr = (const float4*)&kp_s[p][co];
            float acc = 0.f;
#pragma unroll
            for (int c4 = 0; c4 < 4; ++c4) {
                float4 k4 = kr[c4];
                acc += qv[4*c4+0]*k4.x + qv[4*c4+1]*k4.y + qv[4*c4+2]*k4.z + qv[4*c4+3]*k4.w;
            }
            acc += __shfl_xor(acc, 1);
            const int idx = rpi[(size_t)n * 64 + p];
            s8[k] = acc + cpbT[(size_t)idx * 8 + h];
        }
        float cmax = s8[0];
#pragma unroll
        for (int k = 1; k < 8; ++k) cmax = fmaxf(cmax, s8[k]);
        const float m_new = fmaxf(m, cmax);
        const float factor = __expf(m - m_new);   // ==1 when no new max
        Z *= factor;
#pragma unroll
        for (int d = 0; d < 16; ++d) o[d] *= factor;
        m = m_new;
#pragma unroll
        for (int k = 0; k < 8; ++k) {
            const float a = __expf(s8[k] - m);
            Z += a;
            const float4* vr = (const float4*)&vp_s[cch * 8 + k][co];
#pragma unroll
            for (int c4 = 0; c4 < 4; ++c4) {
                float4 v4 = vr[c4];
                o[4*c4+0] += a * v4.x; o[4*c4+1] += a * v4.y;
                o[4*c4+2] += a * v4.z; o[4*c4+3] += a * v4.w;
            }
        }
    }

    // ---- finish softmax: local exps with final m (overwrite sl) ----
#pragma unroll
    for (int l = 0; l < 9; ++l) { sl[l] = __expf(sl[l] - m); Z += sl[l]; }
    const float invZ = 1.0f / Z;
#pragma unroll
    for (int d = 0; d < 16; ++d) o[d] *= invZ;

    // ---- local AV (coef = a_local + lt; zero at OOB since v is zero-pad) ----
#pragma unroll
    for (int l = 0; l < 9; ++l) {
        const int di = l / 3 - 1, dj = l % 3 - 1;
        const int ii = i + di;
        const int jn = j + dj;
        const bool ok = (ii >= 0) && (ii < 64) && (jn >= 0) && (jn < 64);
        const int ic = max(min(ii, 63), 0);
        const int jc = max(min(jn, 63), 0);
        const float coef = ok ? (sl[l] * invZ + lt[l]) : 0.f;
        const float4* vr = (const float4*)(kv + ((size_t)(b * 4096 + ic * 64 + jc)) * 512 + 256 + h * 32 + co);
#pragma unroll
        for (int c4 = 0; c4 < 4; ++c4) {
            float4 v4 = vr[c4];
            o[4*c4+0] += coef * v4.x; o[4*c4+1] += coef * v4.y;
            o[4*c4+2] += coef * v4.z; o[4*c4+3] += coef * v4.w;
        }
    }

    // ---- store 16 bf16 (32 B per lane; pair covers 64 B contiguous) ----
    ushort4* outp = (ushort4*)(attno_bf + gq * 256 + h * 32 + co);
#pragma unroll
    for (int c4 = 0; c4 < 4; ++c4) {
        ushort4 u;
        u.x = f2bf(o[4*c4+0]); u.y = f2bf(o[4*c4+1]);
        u.z = f2bf(o[4*c4+2]); u.w = f2bf(o[4*c4+3]);
        outp[c4] = u;
    }
}

extern "C" void kernel_launch(void* const* d_in, const int* in_sizes, int n_in,
                              void* d_out, int out_size, void* d_ws, size_t ws_size,
                              hipStream_t stream)
{
    const float* x    = (const float*)d_in[0];
    const float* tbl  = (const float*)d_in[1];
    const float* sls  = (const float*)d_in[2];
    const float* q_w  = (const float*)d_in[3];
    const float* q_b  = (const float*)d_in[4];
    const float* kv_w = (const float*)d_in[5];
    const float* kv_b = (const float*)d_in[6];
    const float* temp = (const float*)d_in[7];
    const float* qe   = (const float*)d_in[8];
    const float* sr_w = (const float*)d_in[9];
    const float* sr_b = (const float*)d_in[10];
    const float* ng   = (const float*)d_in[11];
    const float* nb   = (const float*)d_in[12];
    const float* f1w  = (const float*)d_in[13];
    const float* f1b  = (const float*)d_in[14];
    const float* f2w  = (const float*)d_in[15];
    const float* f2b  = (const float*)d_in[16];
    const float* rbl  = (const float*)d_in[17];
    const float* ltok = (const float*)d_in[18];
    const float* lbias= (const float*)d_in[19];
    const float* pw   = (const float*)d_in[20];
    const float* pb   = (const float*)d_in[21];
    const int*   rpi  = (const int*)d_in[22];

    const int C = 256, Hh = 64, Ww = 64, Nn = Hh * Ww;
    const int B = in_sizes[0] / (Nn * C);   // 4
    const int T = in_sizes[1] / 2;
    const int M = B * Nn;                   // 16384

    float* ws = (float*)d_ws;
    size_t o = 0;
    float* qbuf  = ws + o; o += (size_t)M * C;
    float* kvbuf = ws + o; o += (size_t)M * 2 * C;
    float* xsr   = ws + o; o += (size_t)M * C;
    float* xpool = ws + o; o += (size_t)B * 64 * C;
    float* kvp   = ws + o; o += (size_t)B * 64 * 2 * C;
    float* cpbB  = ws + o; o += (size_t)T * 8;
    ushort_t* xhi = (ushort_t*)(ws + o); o += (size_t)M * C / 2;   // reused as attno_bf
    ushort_t* xlo = (ushort_t*)(ws + o); o += (size_t)M * C / 2;
    ushort_t* Wqkh = (ushort_t*)(ws + o); o += 512 * 256 / 2;
    ushort_t* Wqkl = (ushort_t*)(ws + o); o += 512 * 256 / 2;
    ushort_t* Wvs  = (ushort_t*)(ws + o); o += 512 * 256 / 2;
    ushort_t* Pwbf = (ushort_t*)(ws + o); o += 256 * 256 / 2;
    float* bqk = ws + o; o += 512;
    float* bvs = ws + o; o += 512;
    ushort_t* attno_bf = xhi;   // xhi dead after the two x-GEMMs

    dim3 blk(256);
    const int n4x = M * C / 4;

    // prepack
    cast_split<<<(n4x + 255) / 256, blk, 0, stream>>>((const float4*)x, (ushort4*)xhi, (ushort4*)xlo, n4x);
    pack_weights<<<512, blk, 0, stream>>>(q_w, kv_w, sr_w, pw, q_b, kv_b, sr_b,
                                          Wqkh, Wqkl, Wvs, Pwbf, bqk, bvs);
    // [q | k] split-precision GEMM; [v | sr] plain GEMM
    mfma_gemm<true ><<<dim3(4, M / 128), blk, 0, stream>>>(xhi, xlo, Wqkh, Wqkl, bqk, qbuf, kvbuf, 0);
    mfma_gemm<false><<<dim3(4, M / 128), blk, 0, stream>>>(xhi, xlo, Wvs,  Wvs,  bvs, kvbuf, xsr, 1);
    // normalize k (q is normalized in-lane inside attn_v5)
    headnorm<<<M, blk, 0, stream>>>(kvbuf, 2 * C);
    // pool + LN -> kv_p (fp32 GEMM, tiny) -> normalize k_pool
    pool_ln<<<B * 64, blk, 0, stream>>>(xsr, ng, nb, xpool, Hh, Ww);
    gemm_bias_act<<<dim3(2 * C / BN, (B * 64) / BM), blk, 0, stream>>>(xpool, kv_w, kv_b, kvp, B * 64, 2 * C, C, 0);
    headnorm<<<B * 64, blk, 0, stream>>>(kvp, 2 * C);
    // cpb
    cpb_mlp<<<T, blk, 0, stream>>>(tbl, f1w, f1b, f2w, f2b, cpbB);
    // attention (writes bf16 directly); grid: 32 blocks x 8 heads x B
    attn_v5<<<dim3(32, 8, B), blk, 0, stream>>>(
        qbuf, kvbuf, kvp, cpbB, rpi, sls, temp, qe, rbl, ltok, lbias, attno_bf);
    // proj (plain bf16 MFMA)
    mfma_gemm<false><<<dim3(2, M / 128), blk, 0, stream>>>(attno_bf, attno_bf, Pwbf, Pwbf, pb, (float*)d_out, (float*)d_out, 2);
}